// Round 11
// baseline (816.316 us; speedup 1.0000x reference)
//
#include <hip/hip_runtime.h>
#include <hip/hip_bf16.h>
#include <math.h>

#define B_ 16
#define T_ 64
#define C_ 64
#define W_ 256
#define H_ 128
#define CH_ 192   // C_ + H_
#define K_ 5

#define OUT_SEQ_ELEMS ((size_t)B_ * T_ * H_ * W_)            // 33,554,432
#define OUT_H_OFF     OUT_SEQ_ELEMS                          // final h [B,H,W]
#define OUT_C_OFF     (OUT_SEQ_ELEMS + (size_t)B_ * H_ * W_) // final c [B,H,W]

// ---- workspace layout (bytes) ----
#define WS_WF_OFF  0                              // Wfrag bf16: 983040 B
#define WS_XT_OFF  (983040)                       // xT bf16 [B][T][W][C] = 33554432 B
#define WS_HT_OFF  (WS_XT_OFF + 33554432)         // 2 x hT bf16 [B][W][H] = 1 MB each
#define WS_CNT_OFF (WS_HT_OFF + 2 * 1048576)      // 16 padded counters (64B stride)

typedef __attribute__((ext_vector_type(8))) short bf16x8;
typedef __attribute__((ext_vector_type(4))) float f32x4;
typedef __attribute__((ext_vector_type(4))) unsigned int u32x4;

__device__ __forceinline__ float sigmoid_f(float x) {
    return 1.0f / (1.0f + __expf(-x));
}
__device__ __forceinline__ float tanh_f(float x) {
    return 1.0f - 2.0f / (__expf(2.0f * x) + 1.0f);
}

// ---------- prep: weights -> MFMA fragment-major bf16 ----------
__global__ __launch_bounds__(256)
void prep_wfrag(const float* __restrict__ Wc, __hip_bfloat16* __restrict__ wf) {
    int idx = blockIdx.x * 256 + threadIdx.x;
    if (idx >= 960 * 64) return;
    int lane  = idx & 63;
    int f     = idx >> 6;
    int chunk = f % 6;
    int ktap  = (f / 6) % 5;
    int g     = (f / 30) % 4;
    int ht    = f / 120;
    int chan  = g * 128 + ht * 16 + (lane & 15);
    int ci0   = chunk * 32 + 8 * (lane >> 4);
    __hip_bfloat16 tmp[8];
#pragma unroll
    for (int j = 0; j < 8; ++j)
        tmp[j] = __float2bfloat16(Wc[((size_t)chan * CH_ + (ci0 + j)) * K_ + ktap]);
    *reinterpret_cast<u32x4*>(&wf[(size_t)idx * 8]) = *reinterpret_cast<const u32x4*>(tmp);
}

// ---------- prep: x [B,T,C,W] f32 -> xT [B,T,W,C] bf16 ----------
__global__ __launch_bounds__(256)
void prep_xt(const float* __restrict__ x, __hip_bfloat16* __restrict__ xt) {
    __shared__ float tile[64][65];
    int bt = blockIdx.x;
    int w0 = blockIdx.y * 64;
    const float* src = x + (size_t)bt * C_ * W_ + w0;
#pragma unroll
    for (int i = 0; i < 16; ++i) {
        int idx = i * 256 + threadIdx.x;
        int ci = idx >> 6, wr = idx & 63;
        tile[ci][wr] = src[(size_t)ci * W_ + wr];
    }
    __syncthreads();
    __hip_bfloat16* dst = xt + ((size_t)bt * W_ + w0) * C_;
#pragma unroll
    for (int i = 0; i < 8; ++i) {
        int idx = i * 256 + threadIdx.x;
        int wr = idx >> 5, cp = (idx & 31) * 2;
        __hip_bfloat16 a = __float2bfloat16(tile[cp][wr]);
        __hip_bfloat16 b = __float2bfloat16(tile[cp + 1][wr]);
        ushort2 v;
        v.x = *reinterpret_cast<unsigned short*>(&a);
        v.y = *reinterpret_cast<unsigned short*>(&b);
        *reinterpret_cast<ushort2*>(&dst[(size_t)wr * C_ + cp]) = v;
    }
}

__global__ void init_cnt(unsigned int* cnt) {
    if (threadIdx.x < 16 * 16) cnt[threadIdx.x] = 0;
}

// ---------- persistent kernel: all 64 steps ----------
// 256 blocks, 1/CU. Wave split = (gate-pair gp, position-half nh):
// each wave holds 2 gates' weights (60 frags, 240 VGPR) and computes 64
// positions -> each B-frag LDS read feeds 2 MFMAs (was 1), halving the
// dominant LDS-read throughput cost (960->480 ds_read_b128 /CU/step).
// x-only MFMA chunks + x(t+1) staging run BEFORE the h spin-wait.
#define NROWS   132                 // 128 positions + 4 halo
#define XPITCH  128                 // x-region row bytes (64 ci * 2B)
#define HPITCH  256                 // h-region row bytes (128 ci * 2B)
#define XOFF    0                   // x-region: 132*128 = 16896 B
#define HOFF    16896               // h-region: 132*256 = 33792 B
#define GBUF_OFF 50688              // f32 [4][16][128] = 32768 B
#define HBF_OFF  (50688 + 32768)    // bf16 [128][24]   = 6144 B (total 89600)

__global__ __launch_bounds__(256, 1)
void lstm_persistent(const __hip_bfloat16* __restrict__ xt,
                     const __hip_bfloat16* __restrict__ wf,
                     const float* __restrict__ bc,
                     __hip_bfloat16* __restrict__ hbuf0,
                     __hip_bfloat16* __restrict__ hbuf1,
                     float* __restrict__ out,
                     unsigned int* __restrict__ cnt)
{
    __shared__ char lds[89600];
    const int ht   = blockIdx.x;         // 0..7
    const int wseg = blockIdx.y;         // 0..1
    const int b    = blockIdx.z;         // 0..15
    const int tid  = threadIdx.x;
    const int lane = tid & 63;
    const int wid  = tid >> 6;           // 0..3
    const int gp   = wid & 1;            // gate pair: 0 -> {i,f}, 1 -> {o,g}
    const int nh   = wid >> 1;           // position half: 0 -> pos 0-63, 1 -> 64-127
    const int l15  = lane & 15;
    const int lg   = lane >> 4;
    unsigned int* cntb = cnt + b * 16;

    // ---- persistent state: 2 gates' weights in VGPRs, bias, c-state ----
    bf16x8 wreg[2][30];
#pragma unroll
    for (int gl = 0; gl < 2; ++gl) {
        const __hip_bfloat16* wfbase =
            wf + (size_t)(ht * 4 + 2 * gp + gl) * 30 * 512 + (size_t)lane * 8;
#pragma unroll
        for (int f = 0; f < 30; ++f)
            wreg[gl][f] = *reinterpret_cast<const bf16x8*>(wfbase + (size_t)f * 512);
    }
    float bias[2][4];
#pragma unroll
    for (int gl = 0; gl < 2; ++gl) {
        int chanbase = (2 * gp + gl) * 128 + ht * 16 + (lg << 2);
#pragma unroll
        for (int r = 0; r < 4; ++r) bias[gl][r] = bc[chanbase + r];
    }
    float cstate[8];
#pragma unroll
    for (int i = 0; i < 8; ++i) cstate[i] = 0.0f;

    const int wbase = wseg * 128 - 2;
    const int cib = 16 * lg;

    // ---- prologue: stage x(0); zero h-region (t==0 sees zero h) ----
    {
        const __hip_bfloat16* xrow0 = xt + ((size_t)(b * T_ + 0) * W_) * C_;
        for (int idx = tid; idx < NROWS * 8; idx += 256) {
            int wrel = idx >> 3;
            int c16  = idx & 7;
            int w = wbase + wrel;
            u32x4 v = {0u, 0u, 0u, 0u};
            if (w >= 0 && w < W_)
                v = *reinterpret_cast<const u32x4*>(xrow0 + (size_t)w * C_ + c16 * 8);
            int byteoff = XOFF + wrel * XPITCH + ((c16 * 16) ^ ((wrel & 7) << 4));
            *reinterpret_cast<u32x4*>(lds + byteoff) = v;
        }
        for (int idx = tid; idx < NROWS * 16; idx += 256) {
            int wrel = idx >> 4;
            int slot = idx & 15;
            int byteoff = HOFF + wrel * HPITCH + ((slot * 16) ^ ((wrel & 7) << 4));
            u32x4 z = {0u, 0u, 0u, 0u};
            *reinterpret_cast<u32x4*>(lds + byteoff) = z;
        }
    }
    __syncthreads();

    for (int t = 0; t < T_; ++t) {
        const __hip_bfloat16* hrow = ((t & 1) ? hbuf0 : hbuf1) + (size_t)b * W_ * H_;
        __hip_bfloat16* hout = ((t & 1) ? hbuf1 : hbuf0);

        // ---- acc init + x-only MFMA (chunks 0,1; x(t) staged last iter) ----
        f32x4 acc[2][4];
#pragma unroll
        for (int gl = 0; gl < 2; ++gl)
#pragma unroll
            for (int nf = 0; nf < 4; ++nf) {
                acc[gl][nf][0] = bias[gl][0]; acc[gl][nf][1] = bias[gl][1];
                acc[gl][nf][2] = bias[gl][2]; acc[gl][nf][3] = bias[gl][3];
            }
#pragma unroll
        for (int c = 0; c < 2; ++c)
#pragma unroll
            for (int k = 0; k < K_; ++k) {
#pragma unroll
                for (int nf = 0; nf < 4; ++nf) {
                    int wrel = (nh * 4 + nf) * 16 + l15 + k;
                    int byteoff = XOFF + wrel * XPITCH +
                                  ((c * 64 + cib) ^ ((wrel & 7) << 4));
                    bf16x8 bfrag = *reinterpret_cast<const bf16x8*>(lds + byteoff);
                    acc[0][nf] = __builtin_amdgcn_mfma_f32_16x16x32_bf16(
                        wreg[0][k * 6 + c], bfrag, acc[0][nf], 0, 0, 0);
                    acc[1][nf] = __builtin_amdgcn_mfma_f32_16x16x32_bf16(
                        wreg[1][k * 6 + c], bfrag, acc[1][nf], 0, 0, 0);
                }
            }
        __syncthreads();                       // Bx: x(t) fully consumed

        // ---- stage x(t+1) (off critical path) ----
        if (t + 1 < T_) {
            const __hip_bfloat16* xrow = xt + ((size_t)(b * T_ + t + 1) * W_) * C_;
            for (int idx = tid; idx < NROWS * 8; idx += 256) {
                int wrel = idx >> 3;
                int c16  = idx & 7;
                int w = wbase + wrel;
                u32x4 v = {0u, 0u, 0u, 0u};
                if (w >= 0 && w < W_)
                    v = *reinterpret_cast<const u32x4*>(xrow + (size_t)w * C_ + c16 * 8);
                int byteoff = XOFF + wrel * XPITCH + ((c16 * 16) ^ ((wrel & 7) << 4));
                *reinterpret_cast<u32x4*>(lds + byteoff) = v;
            }
        }

        // ---- wait for h(t-1) from all 16 blocks of this batch ----
        if (t > 0) {
            if (tid == 0) {
                unsigned int target = 16u * (unsigned int)t;
                while (__hip_atomic_load(cntb, __ATOMIC_RELAXED, __HIP_MEMORY_SCOPE_AGENT) < target)
                    __builtin_amdgcn_s_sleep(1);
            }
        }
        __syncthreads();                       // B1: h ready + x staged
        __atomic_signal_fence(__ATOMIC_SEQ_CST);

        // ---- h sc1 loads -> LDS h-region ----
        if (t > 0) {
            u32x4 hv[8];
            u32x4 hv8 = {0u, 0u, 0u, 0u};
            const u32x4 zz = {0u, 0u, 0u, 0u};
#pragma unroll
            for (int i = 0; i < 8; ++i) {
                int idx  = i * 256 + tid;
                int wrel = idx >> 4;
                int slot = idx & 15;
                int w = wbase + wrel;
                hv[i] = zz;
                if (w >= 0 && w < W_) {
                    const __hip_bfloat16* hp = hrow + (size_t)w * H_ + slot * 8;
                    asm volatile("global_load_dwordx4 %0, %1, off sc1"
                                 : "+v"(hv[i]) : "v"(hp));
                }
            }
            if (tid < 64) {
                int idx  = 2048 + tid;
                int wrel = idx >> 4;
                int slot = idx & 15;
                int w = wbase + wrel;
                if (w >= 0 && w < W_) {
                    const __hip_bfloat16* hp = hrow + (size_t)w * H_ + slot * 8;
                    asm volatile("global_load_dwordx4 %0, %1, off sc1"
                                 : "+v"(hv8) : "v"(hp));
                }
            }
            asm volatile("s_waitcnt vmcnt(0)" ::: "memory");
            __builtin_amdgcn_sched_barrier(0);
#pragma unroll
            for (int i = 0; i < 8; ++i) {
                int idx  = i * 256 + tid;
                int wrel = idx >> 4;
                int slot = idx & 15;
                int byteoff = HOFF + wrel * HPITCH + ((slot * 16) ^ ((wrel & 7) << 4));
                *reinterpret_cast<u32x4*>(lds + byteoff) = hv[i];
            }
            if (tid < 64) {
                int idx  = 2048 + tid;
                int wrel = idx >> 4;
                int slot = idx & 15;
                int byteoff = HOFF + wrel * HPITCH + ((slot * 16) ^ ((wrel & 7) << 4));
                *reinterpret_cast<u32x4*>(lds + byteoff) = hv8;
            }
        }
        __syncthreads();                       // B2: h columns ready

        // ---- h MFMA (chunks 2..5): one B-read feeds both gates ----
#pragma unroll
        for (int c = 2; c < 6; ++c)
#pragma unroll
            for (int k = 0; k < K_; ++k) {
#pragma unroll
                for (int nf = 0; nf < 4; ++nf) {
                    int wrel = (nh * 4 + nf) * 16 + l15 + k;
                    int byteoff = HOFF + wrel * HPITCH +
                                  (((c - 2) * 64 + cib) ^ ((wrel & 7) << 4));
                    bf16x8 bfrag = *reinterpret_cast<const bf16x8*>(lds + byteoff);
                    acc[0][nf] = __builtin_amdgcn_mfma_f32_16x16x32_bf16(
                        wreg[0][k * 6 + c], bfrag, acc[0][nf], 0, 0, 0);
                    acc[1][nf] = __builtin_amdgcn_mfma_f32_16x16x32_bf16(
                        wreg[1][k * 6 + c], bfrag, acc[1][nf], 0, 0, 0);
                }
            }

        // ---- gates -> dedicated gbuf ----
        float* gbuf = reinterpret_cast<float*>(lds + GBUF_OFF);   // [4][16][128]
        {
            int rowb = lg << 2;
#pragma unroll
            for (int gl = 0; gl < 2; ++gl) {
                int grow = (2 * gp + gl) * 16 + rowb;
#pragma unroll
                for (int nf = 0; nf < 4; ++nf) {
                    int col = (nh * 4 + nf) * 16 + l15;
#pragma unroll
                    for (int r = 0; r < 4; ++r)
                        gbuf[(grow + r) * 128 + col] = acc[gl][nf][r];
                }
            }
        }
        __syncthreads();                       // B3: gbuf complete

        // ---- gating: c + h in registers; bf16 h -> hbf for publish ----
        __hip_bfloat16* hbf = reinterpret_cast<__hip_bfloat16*>(lds + HBF_OFF); // [128][24]
        float hn_r[8];
#pragma unroll
        for (int i = 0; i < 8; ++i) {
            int idx  = i * 256 + tid;
            int chan = idx >> 7;
            int pos  = idx & 127;
            float vi = gbuf[(0 * 16 + chan) * 128 + pos];
            float vf = gbuf[(1 * 16 + chan) * 128 + pos];
            float vo = gbuf[(2 * 16 + chan) * 128 + pos];
            float vg = gbuf[(3 * 16 + chan) * 128 + pos];
            float ii = sigmoid_f(vi), ff = sigmoid_f(vf), oo = sigmoid_f(vo), gg = tanh_f(vg);
            float cn = ff * cstate[i] + ii * gg;
            cstate[i] = cn;
            float hn = oo * tanh_f(cn);
            hn_r[i] = hn;
            hbf[pos * 24 + chan] = __float2bfloat16(hn);
        }
        __syncthreads();                       // B4: hbf complete

        // ---- publish hT (dwordx4 sc1 -> LLC), then signal ----
        {
            int w = tid >> 1, grp = tid & 1;
            u32x4 v = *reinterpret_cast<const u32x4*>(lds + HBF_OFF + w * 48 + grp * 16);
            __hip_bfloat16* hp = hout + ((size_t)b * W_ + wseg * 128 + w) * H_ + ht * 16 + grp * 8;
            asm volatile("global_store_dwordx4 %0, %1, off sc1" :: "v"(hp), "v"(v) : "memory");
        }
        asm volatile("s_waitcnt vmcnt(0)" ::: "memory");
        __syncthreads();                       // B5: all stores landed
        if (tid == 0)
            __hip_atomic_fetch_add(cntb, 1u, __ATOMIC_RELAXED, __HIP_MEMORY_SCOPE_AGENT);

        // ---- deferred (off critical path): fp32 out writes ----
        float* hw = out + ((size_t)(b * T_ + t) * H_ + ht * 16) * W_ + wseg * 128;
#pragma unroll
        for (int i = 0; i < 8; ++i) {
            int idx  = i * 256 + tid;
            int chan = idx >> 7;
            int pos  = idx & 127;
            hw[(size_t)chan * W_ + pos] = hn_r[i];
        }
        if (t == T_ - 1) {
#pragma unroll
            for (int i = 0; i < 8; ++i) {
                int idx  = i * 256 + tid;
                int chan = idx >> 7;
                int pos  = idx & 127;
                out[OUT_H_OFF + ((size_t)b * H_ + ht * 16 + chan) * W_ + wseg * 128 + pos] = hn_r[i];
                out[OUT_C_OFF + ((size_t)b * H_ + ht * 16 + chan) * W_ + wseg * 128 + pos] = cstate[i];
            }
        }
    }
}

extern "C" void kernel_launch(void* const* d_in, const int* in_sizes, int n_in,
                              void* d_out, int out_size, void* d_ws, size_t ws_size,
                              hipStream_t stream)
{
    const float* x  = (const float*)d_in[0];
    const float* Wc = (const float*)d_in[1];
    const float* bc = (const float*)d_in[2];
    float* out = (float*)d_out;
    char*  ws  = (char*)d_ws;

    __hip_bfloat16* wf  = (__hip_bfloat16*)(ws + WS_WF_OFF);
    __hip_bfloat16* xt  = (__hip_bfloat16*)(ws + WS_XT_OFF);
    __hip_bfloat16* hb0 = (__hip_bfloat16*)(ws + WS_HT_OFF);
    __hip_bfloat16* hb1 = (__hip_bfloat16*)(ws + WS_HT_OFF + 1048576);
    unsigned int*   cnt = (unsigned int*)(ws + WS_CNT_OFF);

    prep_wfrag<<<240, 256, 0, stream>>>(Wc, wf);
    prep_xt<<<dim3(B_ * T_, 4), 256, 0, stream>>>(x, xt);
    init_cnt<<<1, 256, 0, stream>>>(cnt);

    lstm_persistent<<<dim3(8, 2, B_), 256, 0, stream>>>(xt, wf, bc, hb0, hb1, out, cnt);
}

// Round 14
// 785.778 us; speedup vs baseline: 1.0389x; 1.0389x over previous
//
#include <hip/hip_runtime.h>
#include <hip/hip_bf16.h>
#include <math.h>

#define B_ 16
#define T_ 64
#define C_ 64
#define W_ 256
#define H_ 128
#define CH_ 192   // C_ + H_
#define K_ 5

#define OUT_SEQ_ELEMS ((size_t)B_ * T_ * H_ * W_)            // 33,554,432
#define OUT_H_OFF     OUT_SEQ_ELEMS                          // final h [B,H,W]
#define OUT_C_OFF     (OUT_SEQ_ELEMS + (size_t)B_ * H_ * W_) // final c [B,H,W]

// ---- workspace layout (bytes) ----
#define WS_WF_OFF  0                              // Wfrag bf16: 983040 B
#define WS_XT_OFF  (983040)                       // xT bf16 [B][T][W][C] = 33554432 B
#define WS_HT_OFF  (WS_XT_OFF + 33554432)         // 2 x hT bf16 [B][W][H] = 1 MB each
#define WS_CNT_OFF (WS_HT_OFF + 2 * 1048576)      // slots: 16 b x 16 prod x 16 u32 = 16 KB

typedef __attribute__((ext_vector_type(8))) short bf16x8;
typedef __attribute__((ext_vector_type(4))) float f32x4;
typedef __attribute__((ext_vector_type(4))) unsigned int u32x4;

__device__ __forceinline__ float sigmoid_f(float x) {
    return 1.0f / (1.0f + __expf(-x));
}
__device__ __forceinline__ float tanh_f(float x) {
    return 1.0f - 2.0f / (__expf(2.0f * x) + 1.0f);
}

// ---------- prep: weights -> MFMA fragment-major bf16 ----------
__global__ __launch_bounds__(256)
void prep_wfrag(const float* __restrict__ Wc, __hip_bfloat16* __restrict__ wf) {
    int idx = blockIdx.x * 256 + threadIdx.x;
    if (idx >= 960 * 64) return;
    int lane  = idx & 63;
    int f     = idx >> 6;
    int chunk = f % 6;
    int ktap  = (f / 6) % 5;
    int g     = (f / 30) % 4;
    int ht    = f / 120;
    int chan  = g * 128 + ht * 16 + (lane & 15);
    int ci0   = chunk * 32 + 8 * (lane >> 4);
    __hip_bfloat16 tmp[8];
#pragma unroll
    for (int j = 0; j < 8; ++j)
        tmp[j] = __float2bfloat16(Wc[((size_t)chan * CH_ + (ci0 + j)) * K_ + ktap]);
    *reinterpret_cast<u32x4*>(&wf[(size_t)idx * 8]) = *reinterpret_cast<const u32x4*>(tmp);
}

// ---------- prep: x [B,T,C,W] f32 -> xT [B,T,W,C] bf16 ----------
__global__ __launch_bounds__(256)
void prep_xt(const float* __restrict__ x, __hip_bfloat16* __restrict__ xt) {
    __shared__ float tile[64][65];
    int bt = blockIdx.x;
    int w0 = blockIdx.y * 64;
    const float* src = x + (size_t)bt * C_ * W_ + w0;
#pragma unroll
    for (int i = 0; i < 16; ++i) {
        int idx = i * 256 + threadIdx.x;
        int ci = idx >> 6, wr = idx & 63;
        tile[ci][wr] = src[(size_t)ci * W_ + wr];
    }
    __syncthreads();
    __hip_bfloat16* dst = xt + ((size_t)bt * W_ + w0) * C_;
#pragma unroll
    for (int i = 0; i < 8; ++i) {
        int idx = i * 256 + threadIdx.x;
        int wr = idx >> 5, cp = (idx & 31) * 2;
        __hip_bfloat16 a = __float2bfloat16(tile[cp][wr]);
        __hip_bfloat16 b = __float2bfloat16(tile[cp + 1][wr]);
        ushort2 v;
        v.x = *reinterpret_cast<unsigned short*>(&a);
        v.y = *reinterpret_cast<unsigned short*>(&b);
        *reinterpret_cast<ushort2*>(&dst[(size_t)wr * C_ + cp]) = v;
    }
}

__global__ void init_cnt(unsigned int* cnt) {
    cnt[blockIdx.x * 256 + threadIdx.x] = 0;   // 16 blocks x 256 = 4096 u32
}

// ---------- persistent kernel: all 64 steps ----------
// 256 blocks, 1/CU, always co-resident (4 waves, 83456B LDS, <=512 VGPR).
// Cross-block exchange uses ONLY primitives proven on this HW (R5-R10):
//   - h data: inline-asm global_{load,store}_dwordx4 sc1 (coherent via LLC)
//   - signaling: compiler AGENT-relaxed atomic store/load (per-producer slots,
//     padded to 64B; consumers poll all 16 lane-parallel in wave 0).
// No RMW counter (removes 16-deep LLC fetch_add serialization); no sc0/XCD
// experiments (R12/R13 post-mortem: unverifiable L1 semantics -> hangs).
#define PITCH_B 384   // bytes per combT row (192 ci * 2B), XOR-swizzled
#define NROWS   132   // 128 positions + 4 halo
#define GBUF_OFF 50688            // f32 [64][128] swizzled = 32768 B (total 83456)
#define GIDX2(row, col) ((row) * 128 + ((col) ^ ((((row) >> 2) & 3) << 4)))

__global__ __launch_bounds__(256, 1)
void lstm_persistent(const __hip_bfloat16* __restrict__ xt,
                     const __hip_bfloat16* __restrict__ wf,
                     const float* __restrict__ bc,
                     __hip_bfloat16* __restrict__ hbuf0,
                     __hip_bfloat16* __restrict__ hbuf1,
                     float* __restrict__ out,
                     unsigned int* __restrict__ slots)
{
    __shared__ char lds[83456];
    const int ht   = blockIdx.x;         // 0..7
    const int wseg = blockIdx.y;         // 0..1
    const int b    = blockIdx.z;         // 0..15
    const int hw16 = ht * 2 + wseg;      // producer index within batch
    const int tid  = threadIdx.x;
    const int lane = tid & 63;
    const int g    = tid >> 6;           // wave id == gate
    const int l15  = lane & 15;
    const int lg   = lane >> 4;
    unsigned int* slotb = slots + (size_t)b * 256;   // 16 slots x 16 u32 stride

    // ---- persistent state: weights in VGPRs, bias, c-state ----
    bf16x8 wreg[30];
    {
        const __hip_bfloat16* wfbase = wf + (size_t)(ht * 4 + g) * 30 * 512 + (size_t)lane * 8;
#pragma unroll
        for (int f = 0; f < 30; ++f)
            wreg[f] = *reinterpret_cast<const bf16x8*>(wfbase + (size_t)f * 512);
    }
    float bias[4];
    {
        int chanbase = g * 128 + ht * 16 + (lg << 2);
#pragma unroll
        for (int r = 0; r < 4; ++r) bias[r] = bc[chanbase + r];
    }
    // epilogue mapping: thread owns position epos, channels [ehi*8, ehi*8+8)
    const int epos = tid & 127;
    const int ehi  = tid >> 7;
    float cstate[8];
#pragma unroll
    for (int i = 0; i < 8; ++i) cstate[i] = 0.0f;

    // ---- prologue: zero combT h-columns (t==0 sees zero h) ----
    for (int idx = tid; idx < NROWS * 16; idx += 256) {
        int wrel = idx >> 4;
        int c16  = (idx & 15) + 8;
        int byteoff = wrel * PITCH_B + ((c16 * 16) ^ ((wrel & 7) << 4));
        u32x4 z = {0u, 0u, 0u, 0u};
        *reinterpret_cast<u32x4*>(lds + byteoff) = z;
    }

    const int wbase = wseg * 128 - 2;
    const int cib = 16 * lg;

    for (int t = 0; t < T_; ++t) {
        const __hip_bfloat16* xrow = xt + ((size_t)(b * T_ + t) * W_) * C_;
        const __hip_bfloat16* hrow = ((t & 1) ? hbuf0 : hbuf1) + (size_t)b * W_ * H_;
        __hip_bfloat16* hout = ((t & 1) ? hbuf1 : hbuf0);

        // ---- stage x half of combT (overlaps the wait below) ----
        for (int idx = tid; idx < NROWS * 8; idx += 256) {
            int wrel = idx >> 3;
            int c16  = idx & 7;
            int w = wbase + wrel;
            u32x4 v = {0u, 0u, 0u, 0u};
            if (w >= 0 && w < W_)
                v = *reinterpret_cast<const u32x4*>(xrow + (size_t)w * C_ + c16 * 8);
            int byteoff = wrel * PITCH_B + ((c16 * 16) ^ ((wrel & 7) << 4));
            *reinterpret_cast<u32x4*>(lds + byteoff) = v;
        }

        // ---- wait: all 16 producers' slots >= t (wave 0, lane-parallel) ----
        if (t > 0 && tid < 64) {
            unsigned int tgt = (unsigned int)t;
            const unsigned int* sp = slotb + (lane & 15) * 16;
            while (!__all(__hip_atomic_load(sp, __ATOMIC_RELAXED,
                                            __HIP_MEMORY_SCOPE_AGENT) >= tgt))
                __builtin_amdgcn_s_sleep(1);
        }
        __syncthreads();                       // B1: x staged + h ready
        __atomic_signal_fence(__ATOMIC_SEQ_CST);

        // ---- issue h sc1 loads (no wait yet; coherent via LLC) ----
        u32x4 hv[8];
        u32x4 hv8 = {0u, 0u, 0u, 0u};
        if (t > 0) {
            const u32x4 zz = {0u, 0u, 0u, 0u};
#pragma unroll
            for (int i = 0; i < 8; ++i) {
                int idx  = i * 256 + tid;
                int wrel = idx >> 4;
                int slot = idx & 15;
                int w = wbase + wrel;
                hv[i] = zz;
                if (w >= 0 && w < W_) {
                    const __hip_bfloat16* hp = hrow + (size_t)w * H_ + slot * 8;
                    asm volatile("global_load_dwordx4 %0, %1, off sc1"
                                 : "+v"(hv[i]) : "v"(hp));
                }
            }
            if (tid < 64) {
                int idx  = 2048 + tid;
                int wrel = idx >> 4;
                int slot = idx & 15;
                int w = wbase + wrel;
                if (w >= 0 && w < W_) {
                    const __hip_bfloat16* hp = hrow + (size_t)w * H_ + slot * 8;
                    asm volatile("global_load_dwordx4 %0, %1, off sc1"
                                 : "+v"(hv8) : "v"(hp));
                }
            }
        }

        // ---- acc init + x-only MFMA (chunks 0,1) while h loads fly ----
        f32x4 acc[8];
#pragma unroll
        for (int nf = 0; nf < 8; ++nf) {
            acc[nf][0] = bias[0]; acc[nf][1] = bias[1];
            acc[nf][2] = bias[2]; acc[nf][3] = bias[3];
        }
#pragma unroll
        for (int c = 0; c < 2; ++c) {
#pragma unroll
            for (int k = 0; k < K_; ++k) {
                bf16x8 afrag = wreg[k * 6 + c];
#pragma unroll
                for (int nf = 0; nf < 8; ++nf) {
                    int wrel = nf * 16 + l15 + k;
                    int byteoff = wrel * PITCH_B + ((c * 64 + cib) ^ ((wrel & 7) << 4));
                    bf16x8 bfrag = *reinterpret_cast<const bf16x8*>(lds + byteoff);
                    acc[nf] = __builtin_amdgcn_mfma_f32_16x16x32_bf16(afrag, bfrag, acc[nf], 0, 0, 0);
                }
            }
        }

        // ---- drain h loads, write into combT h-columns ----
        if (t > 0) {
            asm volatile("s_waitcnt vmcnt(0)" ::: "memory");
            __builtin_amdgcn_sched_barrier(0);
#pragma unroll
            for (int i = 0; i < 8; ++i) {
                int idx  = i * 256 + tid;
                int wrel = idx >> 4;
                int c16  = (idx & 15) + 8;
                int byteoff = wrel * PITCH_B + ((c16 * 16) ^ ((wrel & 7) << 4));
                *reinterpret_cast<u32x4*>(lds + byteoff) = hv[i];
            }
            if (tid < 64) {
                int idx  = 2048 + tid;
                int wrel = idx >> 4;
                int c16  = (idx & 15) + 8;
                int byteoff = wrel * PITCH_B + ((c16 * 16) ^ ((wrel & 7) << 4));
                *reinterpret_cast<u32x4*>(lds + byteoff) = hv8;
            }
        }
        __syncthreads();                       // B2: h columns ready

        // ---- h MFMA (chunks 2..5) ----
#pragma unroll
        for (int c = 2; c < 6; ++c) {
#pragma unroll
            for (int k = 0; k < K_; ++k) {
                bf16x8 afrag = wreg[k * 6 + c];
#pragma unroll
                for (int nf = 0; nf < 8; ++nf) {
                    int wrel = nf * 16 + l15 + k;
                    int byteoff = wrel * PITCH_B + ((c * 64 + cib) ^ ((wrel & 7) << 4));
                    bf16x8 bfrag = *reinterpret_cast<const bf16x8*>(lds + byteoff);
                    acc[nf] = __builtin_amdgcn_mfma_f32_16x16x32_bf16(afrag, bfrag, acc[nf], 0, 0, 0);
                }
            }
        }

        // ---- gates -> gbuf (2-way-max bank swizzle) ----
        float* gbuf = reinterpret_cast<float*>(lds + GBUF_OFF);   // [64][128] swz
        {
            int rowb = lg << 2;
#pragma unroll
            for (int nf = 0; nf < 8; ++nf)
#pragma unroll
                for (int r = 0; r < 4; ++r) {
                    int row = g * 16 + rowb + r;
                    gbuf[GIDX2(row, nf * 16 + l15)] = acc[nf][r];
                }
        }
        __syncthreads();                       // B3: gbuf complete

        // ---- gating: 8 consecutive chans at one position; c + h in regs ----
        float hn8[8];
        unsigned int pk[4] = {0u, 0u, 0u, 0u};
#pragma unroll
        for (int j = 0; j < 8; ++j) {
            int chan = ehi * 8 + j;
            float vi = gbuf[GIDX2(0 * 16 + chan, epos)];
            float vf = gbuf[GIDX2(1 * 16 + chan, epos)];
            float vo = gbuf[GIDX2(2 * 16 + chan, epos)];
            float vg = gbuf[GIDX2(3 * 16 + chan, epos)];
            float ii = sigmoid_f(vi), ff = sigmoid_f(vf);
            float oo = sigmoid_f(vo), gg = tanh_f(vg);
            float cn = ff * cstate[j] + ii * gg;
            cstate[j] = cn;
            float hn = oo * tanh_f(cn);
            hn8[j] = hn;
            __hip_bfloat16 hb = __float2bfloat16(hn);
            pk[j >> 1] |= ((unsigned int)*reinterpret_cast<unsigned short*>(&hb)) << (16 * (j & 1));
        }
        u32x4 pv = { pk[0], pk[1], pk[2], pk[3] };

        // ---- publish hT straight from regs (sc1 -> LLC), then signal ----
        {
            __hip_bfloat16* hp = hout + ((size_t)b * W_ + wseg * 128 + epos) * H_
                                      + ht * 16 + ehi * 8;
            asm volatile("global_store_dwordx4 %0, %1, off sc1" :: "v"(hp), "v"(pv) : "memory");
        }
        asm volatile("s_waitcnt vmcnt(0)" ::: "memory");   // publish landed at LLC
        __syncthreads();                       // B4: all publishes landed
        if (tid == 0)
            __hip_atomic_store(slotb + hw16 * 16, (unsigned int)(t + 1),
                               __ATOMIC_RELAXED, __HIP_MEMORY_SCOPE_AGENT);

        // ---- deferred (off critical path): fp32 out writes ----
        float* hw = out + ((size_t)(b * T_ + t) * H_ + ht * 16) * W_ + wseg * 128;
#pragma unroll
        for (int j = 0; j < 8; ++j)
            hw[(size_t)(ehi * 8 + j) * W_ + epos] = hn8[j];
        if (t == T_ - 1) {
#pragma unroll
            for (int j = 0; j < 8; ++j) {
                size_t base = ((size_t)b * H_ + ht * 16 + ehi * 8 + j) * W_ + wseg * 128 + epos;
                out[OUT_H_OFF + base] = hn8[j];
                out[OUT_C_OFF + base] = cstate[j];
            }
        }
    }
}

extern "C" void kernel_launch(void* const* d_in, const int* in_sizes, int n_in,
                              void* d_out, int out_size, void* d_ws, size_t ws_size,
                              hipStream_t stream)
{
    const float* x  = (const float*)d_in[0];
    const float* Wc = (const float*)d_in[1];
    const float* bc = (const float*)d_in[2];
    float* out = (float*)d_out;
    char*  ws  = (char*)d_ws;

    __hip_bfloat16* wf  = (__hip_bfloat16*)(ws + WS_WF_OFF);
    __hip_bfloat16* xt  = (__hip_bfloat16*)(ws + WS_XT_OFF);
    __hip_bfloat16* hb0 = (__hip_bfloat16*)(ws + WS_HT_OFF);
    __hip_bfloat16* hb1 = (__hip_bfloat16*)(ws + WS_HT_OFF + 1048576);
    unsigned int*   cnt = (unsigned int*)(ws + WS_CNT_OFF);

    prep_wfrag<<<240, 256, 0, stream>>>(Wc, wf);
    prep_xt<<<dim3(B_ * T_, 4), 256, 0, stream>>>(x, xt);
    init_cnt<<<16, 256, 0, stream>>>(cnt);

    lstm_persistent<<<dim3(8, 2, B_), 256, 0, stream>>>(xt, wf, bc, hb0, hb1, out, cnt);
}

// Round 15
// 784.778 us; speedup vs baseline: 1.0402x; 1.0013x over previous
//
#include <hip/hip_runtime.h>
#include <hip/hip_bf16.h>
#include <math.h>

#define B_ 16
#define T_ 64
#define C_ 64
#define W_ 256
#define H_ 128
#define CH_ 192   // C_ + H_
#define K_ 5

#define OUT_SEQ_ELEMS ((size_t)B_ * T_ * H_ * W_)            // 33,554,432
#define OUT_H_OFF     OUT_SEQ_ELEMS                          // final h [B,H,W]
#define OUT_C_OFF     (OUT_SEQ_ELEMS + (size_t)B_ * H_ * W_) // final c [B,H,W]

// ---- workspace layout (bytes) ----
#define WS_WF_OFF  0                              // Wfrag bf16: 983040 B
#define WS_XT_OFF  (983040)                       // xT bf16 [B][T][W][C] = 33554432 B
#define WS_HT_OFF  (WS_XT_OFF + 33554432)         // 2 x hT bf16 [B][W][H] = 1 MB each
#define WS_CNT_OFF (WS_HT_OFF + 2 * 1048576)      // slots: 16 b x 16 prod x 16 u32 = 16 KB

typedef __attribute__((ext_vector_type(8))) short bf16x8;
typedef __attribute__((ext_vector_type(4))) float f32x4;
typedef __attribute__((ext_vector_type(4))) unsigned int u32x4;

__device__ __forceinline__ float sigmoid_f(float x) {
    return 1.0f / (1.0f + __expf(-x));
}
__device__ __forceinline__ float tanh_f(float x) {
    return 1.0f - 2.0f / (__expf(2.0f * x) + 1.0f);
}

// ---------- prep: weights -> MFMA fragment-major bf16 ----------
__global__ __launch_bounds__(256)
void prep_wfrag(const float* __restrict__ Wc, __hip_bfloat16* __restrict__ wf) {
    int idx = blockIdx.x * 256 + threadIdx.x;
    if (idx >= 960 * 64) return;
    int lane  = idx & 63;
    int f     = idx >> 6;
    int chunk = f % 6;
    int ktap  = (f / 6) % 5;
    int g     = (f / 30) % 4;
    int ht    = f / 120;
    int chan  = g * 128 + ht * 16 + (lane & 15);
    int ci0   = chunk * 32 + 8 * (lane >> 4);
    __hip_bfloat16 tmp[8];
#pragma unroll
    for (int j = 0; j < 8; ++j)
        tmp[j] = __float2bfloat16(Wc[((size_t)chan * CH_ + (ci0 + j)) * K_ + ktap]);
    *reinterpret_cast<u32x4*>(&wf[(size_t)idx * 8]) = *reinterpret_cast<const u32x4*>(tmp);
}

// ---------- prep: x [B,T,C,W] f32 -> xT [B,T,W,C] bf16 ----------
__global__ __launch_bounds__(256)
void prep_xt(const float* __restrict__ x, __hip_bfloat16* __restrict__ xt) {
    __shared__ float tile[64][65];
    int bt = blockIdx.x;
    int w0 = blockIdx.y * 64;
    const float* src = x + (size_t)bt * C_ * W_ + w0;
#pragma unroll
    for (int i = 0; i < 16; ++i) {
        int idx = i * 256 + threadIdx.x;
        int ci = idx >> 6, wr = idx & 63;
        tile[ci][wr] = src[(size_t)ci * W_ + wr];
    }
    __syncthreads();
    __hip_bfloat16* dst = xt + ((size_t)bt * W_ + w0) * C_;
#pragma unroll
    for (int i = 0; i < 8; ++i) {
        int idx = i * 256 + threadIdx.x;
        int wr = idx >> 5, cp = (idx & 31) * 2;
        __hip_bfloat16 a = __float2bfloat16(tile[cp][wr]);
        __hip_bfloat16 b = __float2bfloat16(tile[cp + 1][wr]);
        ushort2 v;
        v.x = *reinterpret_cast<unsigned short*>(&a);
        v.y = *reinterpret_cast<unsigned short*>(&b);
        *reinterpret_cast<ushort2*>(&dst[(size_t)wr * C_ + cp]) = v;
    }
}

__global__ void init_cnt(unsigned int* cnt) {
    cnt[blockIdx.x * 256 + threadIdx.x] = 0;   // 16 blocks x 256 = 4096 u32
}

// ---------- persistent kernel: all 64 steps ----------
// 256 blocks, 1/CU, always co-resident (4 waves, 83456B LDS, <=512 VGPR).
// Cross-block exchange uses ONLY primitives proven on this HW (R5-R10):
//   - h data: inline-asm global_{load,store}_dwordx4 sc1 (coherent via LLC)
//   - signaling: compiler AGENT-relaxed atomic store/load (per-producer slots,
//     padded to 64B; consumers poll all 16 lane-parallel in wave 0).
// No RMW counter (removes 16-deep LLC fetch_add serialization); no sc0/XCD
// experiments (R12/R13 post-mortem: unverifiable L1 semantics -> hangs).
#define PITCH_B 384   // bytes per combT row (192 ci * 2B), XOR-swizzled
#define NROWS   132   // 128 positions + 4 halo
#define GBUF_OFF 50688            // f32 [64][128] swizzled = 32768 B (total 83456)
#define GIDX2(row, col) ((row) * 128 + ((col) ^ ((((row) >> 2) & 3) << 4)))

__global__ __launch_bounds__(256, 1)
void lstm_persistent(const __hip_bfloat16* __restrict__ xt,
                     const __hip_bfloat16* __restrict__ wf,
                     const float* __restrict__ bc,
                     __hip_bfloat16* __restrict__ hbuf0,
                     __hip_bfloat16* __restrict__ hbuf1,
                     float* __restrict__ out,
                     unsigned int* __restrict__ slots)
{
    __shared__ char lds[83456];
    const int ht   = blockIdx.x;         // 0..7
    const int wseg = blockIdx.y;         // 0..1
    const int b    = blockIdx.z;         // 0..15
    const int hw16 = ht * 2 + wseg;      // producer index within batch
    const int tid  = threadIdx.x;
    const int lane = tid & 63;
    const int g    = tid >> 6;           // wave id == gate
    const int l15  = lane & 15;
    const int lg   = lane >> 4;
    unsigned int* slotb = slots + (size_t)b * 256;   // 16 slots x 16 u32 stride

    // ---- persistent state: weights in VGPRs, bias, c-state ----
    bf16x8 wreg[30];
    {
        const __hip_bfloat16* wfbase = wf + (size_t)(ht * 4 + g) * 30 * 512 + (size_t)lane * 8;
#pragma unroll
        for (int f = 0; f < 30; ++f)
            wreg[f] = *reinterpret_cast<const bf16x8*>(wfbase + (size_t)f * 512);
    }
    float bias[4];
    {
        int chanbase = g * 128 + ht * 16 + (lg << 2);
#pragma unroll
        for (int r = 0; r < 4; ++r) bias[r] = bc[chanbase + r];
    }
    // epilogue mapping: thread owns position epos, channels [ehi*8, ehi*8+8)
    const int epos = tid & 127;
    const int ehi  = tid >> 7;
    float cstate[8];
#pragma unroll
    for (int i = 0; i < 8; ++i) cstate[i] = 0.0f;

    // ---- prologue: zero combT h-columns (t==0 sees zero h) ----
    for (int idx = tid; idx < NROWS * 16; idx += 256) {
        int wrel = idx >> 4;
        int c16  = (idx & 15) + 8;
        int byteoff = wrel * PITCH_B + ((c16 * 16) ^ ((wrel & 7) << 4));
        u32x4 z = {0u, 0u, 0u, 0u};
        *reinterpret_cast<u32x4*>(lds + byteoff) = z;
    }

    const int wbase = wseg * 128 - 2;
    const int cib = 16 * lg;

    for (int t = 0; t < T_; ++t) {
        const __hip_bfloat16* xrow = xt + ((size_t)(b * T_ + t) * W_) * C_;
        const __hip_bfloat16* hrow = ((t & 1) ? hbuf0 : hbuf1) + (size_t)b * W_ * H_;
        __hip_bfloat16* hout = ((t & 1) ? hbuf1 : hbuf0);

        // ---- stage x half of combT (overlaps the wait below) ----
        for (int idx = tid; idx < NROWS * 8; idx += 256) {
            int wrel = idx >> 3;
            int c16  = idx & 7;
            int w = wbase + wrel;
            u32x4 v = {0u, 0u, 0u, 0u};
            if (w >= 0 && w < W_)
                v = *reinterpret_cast<const u32x4*>(xrow + (size_t)w * C_ + c16 * 8);
            int byteoff = wrel * PITCH_B + ((c16 * 16) ^ ((wrel & 7) << 4));
            *reinterpret_cast<u32x4*>(lds + byteoff) = v;
        }

        // ---- wait: all 16 producers' slots >= t (wave 0, lane-parallel) ----
        if (t > 0 && tid < 64) {
            unsigned int tgt = (unsigned int)t;
            const unsigned int* sp = slotb + (lane & 15) * 16;
            while (!__all(__hip_atomic_load(sp, __ATOMIC_RELAXED,
                                            __HIP_MEMORY_SCOPE_AGENT) >= tgt))
                __builtin_amdgcn_s_sleep(1);
        }
        __syncthreads();                       // B1: x staged + h ready
        __atomic_signal_fence(__ATOMIC_SEQ_CST);

        // ---- issue h sc1 loads (no wait yet; coherent via LLC) ----
        u32x4 hv[8];
        u32x4 hv8 = {0u, 0u, 0u, 0u};
        if (t > 0) {
            const u32x4 zz = {0u, 0u, 0u, 0u};
#pragma unroll
            for (int i = 0; i < 8; ++i) {
                int idx  = i * 256 + tid;
                int wrel = idx >> 4;
                int slot = idx & 15;
                int w = wbase + wrel;
                hv[i] = zz;
                if (w >= 0 && w < W_) {
                    const __hip_bfloat16* hp = hrow + (size_t)w * H_ + slot * 8;
                    asm volatile("global_load_dwordx4 %0, %1, off sc1"
                                 : "+v"(hv[i]) : "v"(hp));
                }
            }
            if (tid < 64) {
                int idx  = 2048 + tid;
                int wrel = idx >> 4;
                int slot = idx & 15;
                int w = wbase + wrel;
                if (w >= 0 && w < W_) {
                    const __hip_bfloat16* hp = hrow + (size_t)w * H_ + slot * 8;
                    asm volatile("global_load_dwordx4 %0, %1, off sc1"
                                 : "+v"(hv8) : "v"(hp));
                }
            }
        }

        // ---- acc init + x-only MFMA (chunks 0,1) while h loads fly ----
        f32x4 acc[8];
#pragma unroll
        for (int nf = 0; nf < 8; ++nf) {
            acc[nf][0] = bias[0]; acc[nf][1] = bias[1];
            acc[nf][2] = bias[2]; acc[nf][3] = bias[3];
        }
#pragma unroll
        for (int c = 0; c < 2; ++c) {
#pragma unroll
            for (int k = 0; k < K_; ++k) {
                bf16x8 afrag = wreg[k * 6 + c];
#pragma unroll
                for (int nf = 0; nf < 8; ++nf) {
                    int wrel = nf * 16 + l15 + k;
                    int byteoff = wrel * PITCH_B + ((c * 64 + cib) ^ ((wrel & 7) << 4));
                    bf16x8 bfrag = *reinterpret_cast<const bf16x8*>(lds + byteoff);
                    acc[nf] = __builtin_amdgcn_mfma_f32_16x16x32_bf16(afrag, bfrag, acc[nf], 0, 0, 0);
                }
            }
        }

        // ---- drain h loads, write into combT h-columns ----
        if (t > 0) {
            asm volatile("s_waitcnt vmcnt(0)" ::: "memory");
            __builtin_amdgcn_sched_barrier(0);
#pragma unroll
            for (int i = 0; i < 8; ++i) {
                int idx  = i * 256 + tid;
                int wrel = idx >> 4;
                int c16  = (idx & 15) + 8;
                int byteoff = wrel * PITCH_B + ((c16 * 16) ^ ((wrel & 7) << 4));
                *reinterpret_cast<u32x4*>(lds + byteoff) = hv[i];
            }
            if (tid < 64) {
                int idx  = 2048 + tid;
                int wrel = idx >> 4;
                int c16  = (idx & 15) + 8;
                int byteoff = wrel * PITCH_B + ((c16 * 16) ^ ((wrel & 7) << 4));
                *reinterpret_cast<u32x4*>(lds + byteoff) = hv8;
            }
        }
        __syncthreads();                       // B2: h columns ready

        // ---- h MFMA (chunks 2..5) ----
#pragma unroll
        for (int c = 2; c < 6; ++c) {
#pragma unroll
            for (int k = 0; k < K_; ++k) {
                bf16x8 afrag = wreg[k * 6 + c];
#pragma unroll
                for (int nf = 0; nf < 8; ++nf) {
                    int wrel = nf * 16 + l15 + k;
                    int byteoff = wrel * PITCH_B + ((c * 64 + cib) ^ ((wrel & 7) << 4));
                    bf16x8 bfrag = *reinterpret_cast<const bf16x8*>(lds + byteoff);
                    acc[nf] = __builtin_amdgcn_mfma_f32_16x16x32_bf16(afrag, bfrag, acc[nf], 0, 0, 0);
                }
            }
        }

        // ---- gates -> gbuf (2-way-max bank swizzle) ----
        float* gbuf = reinterpret_cast<float*>(lds + GBUF_OFF);   // [64][128] swz
        {
            int rowb = lg << 2;
#pragma unroll
            for (int nf = 0; nf < 8; ++nf)
#pragma unroll
                for (int r = 0; r < 4; ++r) {
                    int row = g * 16 + rowb + r;
                    gbuf[GIDX2(row, nf * 16 + l15)] = acc[nf][r];
                }
        }
        __syncthreads();                       // B3: gbuf complete

        // ---- gating: 8 consecutive chans at one position; c + h in regs ----
        float hn8[8];
        unsigned int pk[4] = {0u, 0u, 0u, 0u};
#pragma unroll
        for (int j = 0; j < 8; ++j) {
            int chan = ehi * 8 + j;
            float vi = gbuf[GIDX2(0 * 16 + chan, epos)];
            float vf = gbuf[GIDX2(1 * 16 + chan, epos)];
            float vo = gbuf[GIDX2(2 * 16 + chan, epos)];
            float vg = gbuf[GIDX2(3 * 16 + chan, epos)];
            float ii = sigmoid_f(vi), ff = sigmoid_f(vf);
            float oo = sigmoid_f(vo), gg = tanh_f(vg);
            float cn = ff * cstate[j] + ii * gg;
            cstate[j] = cn;
            float hn = oo * tanh_f(cn);
            hn8[j] = hn;
            __hip_bfloat16 hb = __float2bfloat16(hn);
            pk[j >> 1] |= ((unsigned int)*reinterpret_cast<unsigned short*>(&hb)) << (16 * (j & 1));
        }
        u32x4 pv = { pk[0], pk[1], pk[2], pk[3] };

        // ---- publish hT straight from regs (sc1 -> LLC), then signal ----
        {
            __hip_bfloat16* hp = hout + ((size_t)b * W_ + wseg * 128 + epos) * H_
                                      + ht * 16 + ehi * 8;
            asm volatile("global_store_dwordx4 %0, %1, off sc1" :: "v"(hp), "v"(pv) : "memory");
        }
        asm volatile("s_waitcnt vmcnt(0)" ::: "memory");   // publish landed at LLC
        __syncthreads();                       // B4: all publishes landed
        if (tid == 0)
            __hip_atomic_store(slotb + hw16 * 16, (unsigned int)(t + 1),
                               __ATOMIC_RELAXED, __HIP_MEMORY_SCOPE_AGENT);

        // ---- deferred (off critical path): fp32 out writes ----
        float* hw = out + ((size_t)(b * T_ + t) * H_ + ht * 16) * W_ + wseg * 128;
#pragma unroll
        for (int j = 0; j < 8; ++j)
            hw[(size_t)(ehi * 8 + j) * W_ + epos] = hn8[j];
        if (t == T_ - 1) {
#pragma unroll
            for (int j = 0; j < 8; ++j) {
                size_t base = ((size_t)b * H_ + ht * 16 + ehi * 8 + j) * W_ + wseg * 128 + epos;
                out[OUT_H_OFF + base] = hn8[j];
                out[OUT_C_OFF + base] = cstate[j];
            }
        }
    }
}

extern "C" void kernel_launch(void* const* d_in, const int* in_sizes, int n_in,
                              void* d_out, int out_size, void* d_ws, size_t ws_size,
                              hipStream_t stream)
{
    const float* x  = (const float*)d_in[0];
    const float* Wc = (const float*)d_in[1];
    const float* bc = (const float*)d_in[2];
    float* out = (float*)d_out;
    char*  ws  = (char*)d_ws;

    __hip_bfloat16* wf  = (__hip_bfloat16*)(ws + WS_WF_OFF);
    __hip_bfloat16* xt  = (__hip_bfloat16*)(ws + WS_XT_OFF);
    __hip_bfloat16* hb0 = (__hip_bfloat16*)(ws + WS_HT_OFF);
    __hip_bfloat16* hb1 = (__hip_bfloat16*)(ws + WS_HT_OFF + 1048576);
    unsigned int*   cnt = (unsigned int*)(ws + WS_CNT_OFF);

    prep_wfrag<<<240, 256, 0, stream>>>(Wc, wf);
    prep_xt<<<dim3(B_ * T_, 4), 256, 0, stream>>>(x, xt);
    init_cnt<<<16, 256, 0, stream>>>(cnt);

    lstm_persistent<<<dim3(8, 2, B_), 256, 0, stream>>>(xt, wf, bc, hb0, hb1, out, cnt);
}